// Round 13
// baseline (95.373 us; speedup 1.0000x reference)
//
#include <hip/hip_runtime.h>
#include <stdint.h>

typedef short bf16x8 __attribute__((ext_vector_type(8)));
typedef float f32x4 __attribute__((ext_vector_type(4)));

__device__ __forceinline__ unsigned short f2bf(float f) {
  unsigned u = __float_as_uint(f);
  u += 0x7fffu + ((u >> 16) & 1u);   // RNE round to bf16
  return (unsigned short)(u >> 16);
}
__device__ __forceinline__ unsigned umax_(unsigned a, unsigned b) { return a > b ? a : b; }

// ---- k_pre: 640 blocks. bid>=512: emb -> tiled embb + h2s.
//      bid<512: z -> fragment-tiled zb (16 rows/tile, frag=kk*4+l4) + sum z^2.
__global__ __launch_bounds__(256) void k_pre(const float* __restrict__ z,
                                             const float* __restrict__ emb,
                                             unsigned short* __restrict__ embb,
                                             float* __restrict__ h2s,
                                             unsigned short* __restrict__ zb,
                                             float* __restrict__ acc) {
  __shared__ unsigned lds[64 * 128];   // [h][cp ^ (h&28)]
  __shared__ float rsum[4];
  const int t = threadIdx.x;
  const int bid = blockIdx.x;

  if (bid >= 512) {            // ---- prep branch (128 blocks) ----
    const int n = (bid - 512) * 8 + (t >> 5);
    const int c8 = t & 31;
    const float* src = emb + (size_t)n * 256 + c8 * 8;
    float s = 0.f;
    union { bf16x8 v; unsigned short u[8]; } pk;
#pragma unroll
    for (int i = 0; i < 8; ++i) {
      float f = src[i];
      s += f * f;
      pk.u[i] = f2bf(f);
    }
    *(bf16x8*)((char*)embb + (size_t)(n >> 4) * 8192 + (c8 * 16 + (n & 15)) * 16) = pk.v;
#pragma unroll
    for (int m = 1; m < 32; m <<= 1) s += __shfl_xor(s, m);
    if ((t & 31) == 0) h2s[n] = 0.5f * s + 1.0f;   // +1 keeps scores strictly < 0
    return;
  }

  // ---- prez branch (512 blocks): 64 hw-rows x 256 c ----
  const int b = bid >> 4, hwg = bid & 15;
  const int tc = t >> 4, h4 = (t & 15) * 4;
  const float* zp = z + (size_t)b * 262144 + hwg * 64;
  float ss = 0.f;
#pragma unroll
  for (int p = 0; p < 8; ++p) {
    const int cp = p * 16 + tc;                       // c-pair index 0..127
    const float4 v0 = *(const float4*)(zp + (size_t)(2 * cp) * 1024 + h4);
    const float4 v1 = *(const float4*)(zp + (size_t)(2 * cp + 1) * 1024 + h4);
    ss += v0.x * v0.x + v0.y * v0.y + v0.z * v0.z + v0.w * v0.w
        + v1.x * v1.x + v1.y * v1.y + v1.z * v1.z + v1.w * v1.w;
    const unsigned w0 = ((unsigned)f2bf(v1.x) << 16) | (unsigned)f2bf(v0.x);
    const unsigned w1 = ((unsigned)f2bf(v1.y) << 16) | (unsigned)f2bf(v0.y);
    const unsigned w2 = ((unsigned)f2bf(v1.z) << 16) | (unsigned)f2bf(v0.z);
    const unsigned w3 = ((unsigned)f2bf(v1.w) << 16) | (unsigned)f2bf(v0.w);
    lds[(h4 + 0) * 128 + (cp ^ ((h4 + 0) & 28))] = w0;
    lds[(h4 + 1) * 128 + (cp ^ ((h4 + 1) & 28))] = w1;
    lds[(h4 + 2) * 128 + (cp ^ ((h4 + 2) & 28))] = w2;
    lds[(h4 + 3) * 128 + (cp ^ ((h4 + 3) & 28))] = w3;
  }
#pragma unroll
  for (int m = 1; m < 64; m <<= 1) ss += __shfl_xor(ss, m);
  if ((t & 63) == 0) rsum[t >> 6] = ss;
  __syncthreads();
  if (t == 0) atomicAdd(acc, rsum[0] + rsum[1] + rsum[2] + rsum[3]);

  unsigned* zbd = (unsigned*)zb;
  const size_t base_dw = ((size_t)b * 1024 + hwg * 64) * 128;
  const int l15 = t & 15, fr = t >> 4;                // fr 0..15
#pragma unroll
  for (int tile = 0; tile < 4; ++tile) {
    const int r = tile * 16 + l15;
#pragma unroll
    for (int half = 0; half < 2; ++half) {
      const int frag = fr + half * 16;                // 0..31 = kk*4+l4
      const int d = (frag >> 2) * 16 + (frag & 3) * 4;
      uint4 v = *(const uint4*)(&lds[r * 128 + (d ^ (r & 28))]);
      *(uint4*)(zbd + base_dw + tile * 2048 + frag * 64 + l15 * 4) = v;
    }
  }
}

// ---- k_gemm: 512 blocks x 4 waves. Wave = 64 rows (af[4][8] in regs, direct
// from tiled zb) x 256-emb QUARTER (= 131072 B of embb); B asm ping-pong,
// each B-frag feeds 4 MFMAs.
__global__ __launch_bounds__(256, 2) void k_gemm(
    const unsigned short* __restrict__ zb, const unsigned short* __restrict__ embb,
    const float* __restrict__ h2s, const float* __restrict__ emb,
    float* __restrict__ out, float* __restrict__ acc_g,
    unsigned* __restrict__ done, float* __restrict__ lossp) {

  __shared__ __align__(16) float fst[128 * 65];   // epilogue staging (33 KB)
  __shared__ __align__(16) float hL[1024];
  __shared__ unsigned kbuf[4][64];
  __shared__ int sidx[64];

  const int t = threadIdx.x;
  const int lane = t & 63;
  const int w = t >> 6;            // emb quarter
  const int l15 = lane & 15;
  const int l4 = lane >> 4;
  const int rg = blockIdx.x;

  ((float4*)hL)[t] = *(const float4*)(h2s + t * 4);

  // A: 64 rows resident in registers (32 contiguous-1KB loads from tiled zb)
  const char* Az = (const char*)zb + (size_t)rg * 32768 + l4 * 256 + l15 * 16;
  bf16x8 af[4][8];
#pragma unroll
  for (int ti = 0; ti < 4; ++ti)
#pragma unroll
    for (int kk = 0; kk < 8; ++kk)
      af[ti][kk] = *(const bf16x8*)(Az + ti * 8192 + kk * 1024);

  __syncthreads();   // hL visible

  const char* Bp = (const char*)embb;
  // QUARTER stride: 256 embs x 512 B = 131072 B  (R12 bug was w*262144 -> OOB)
  const unsigned off0 = (unsigned)(w * 131072 + l4 * 256 + l15 * 16);
  const unsigned ciob = (unsigned)(1023 - (w * 256 + l15));
  unsigned kb[4][4];
#pragma unroll
  for (int ti = 0; ti < 4; ++ti)
#pragma unroll
    for (int j = 0; j < 4; ++j) kb[ti][j] = 0u;

  bf16x8 bufA[8], bufB[8];

#define LOAD8(DST, OFF, OFFH)                                                                     \
  asm volatile("global_load_dwordx4 %0, %1, %2 offset:0"    : "=v"(DST[0]) : "v"(OFF),  "s"(Bp)); \
  asm volatile("global_load_dwordx4 %0, %1, %2 offset:1024" : "=v"(DST[1]) : "v"(OFF),  "s"(Bp)); \
  asm volatile("global_load_dwordx4 %0, %1, %2 offset:2048" : "=v"(DST[2]) : "v"(OFF),  "s"(Bp)); \
  asm volatile("global_load_dwordx4 %0, %1, %2 offset:3072" : "=v"(DST[3]) : "v"(OFF),  "s"(Bp)); \
  asm volatile("global_load_dwordx4 %0, %1, %2 offset:0"    : "=v"(DST[4]) : "v"(OFFH), "s"(Bp)); \
  asm volatile("global_load_dwordx4 %0, %1, %2 offset:1024" : "=v"(DST[5]) : "v"(OFFH), "s"(Bp)); \
  asm volatile("global_load_dwordx4 %0, %1, %2 offset:2048" : "=v"(DST[6]) : "v"(OFFH), "s"(Bp)); \
  asm volatile("global_load_dwordx4 %0, %1, %2 offset:3072" : "=v"(DST[7]) : "v"(OFFH), "s"(Bp));

  LOAD8(bufA, off0, off0 + 4096u)   // tile 0 in flight

#pragma unroll
  for (int tl = 0; tl < 16; ++tl) {
    bf16x8 (&cur)[8] = (tl & 1) ? bufB : bufA;
    bf16x8 (&nxt)[8] = (tl & 1) ? bufA : bufB;
    if (tl < 15) {
      const unsigned oN = off0 + (unsigned)((tl + 1) * 8192);
      LOAD8(nxt, oN, oN + 4096u)
      asm volatile("s_waitcnt vmcnt(8)" ::: "memory");   // tile tl arrived
    } else {
      asm volatile("s_waitcnt vmcnt(0)" ::: "memory");
    }
    __builtin_amdgcn_sched_barrier(0);                   // rule #18 fence
    const float hv = hL[w * 256 + tl * 16 + l15];
    f32x4 a0{}, a1{}, a2{}, a3{};
#pragma unroll
    for (int kk = 0; kk < 8; ++kk) {
      a0 = __builtin_amdgcn_mfma_f32_16x16x32_bf16(af[0][kk], cur[kk], a0, 0, 0, 0);
      a1 = __builtin_amdgcn_mfma_f32_16x16x32_bf16(af[1][kk], cur[kk], a1, 0, 0, 0);
      a2 = __builtin_amdgcn_mfma_f32_16x16x32_bf16(af[2][kk], cur[kk], a2, 0, 0, 0);
      a3 = __builtin_amdgcn_mfma_f32_16x16x32_bf16(af[3][kk], cur[kk], a3, 0, 0, 0);
    }
    const unsigned cio = ciob - (unsigned)(tl * 16);
#pragma unroll
    for (int j = 0; j < 4; ++j) {
      kb[0][j] = umax_(kb[0][j], (~__float_as_uint(a0[j] - hv) & 0xFFFFFC00u) | cio);
      kb[1][j] = umax_(kb[1][j], (~__float_as_uint(a1[j] - hv) & 0xFFFFFC00u) | cio);
      kb[2][j] = umax_(kb[2][j], (~__float_as_uint(a2[j] - hv) & 0xFFFFFC00u) | cio);
      kb[3][j] = umax_(kb[3][j], (~__float_as_uint(a3[j] - hv) & 0xFFFFFC00u) | cio);
    }
  }
#undef LOAD8

  // ---- 16-lane DPP key-max per (ti,j) -> kbuf[w]
#pragma unroll
  for (int ti = 0; ti < 4; ++ti)
#pragma unroll
    for (int j = 0; j < 4; ++j) {
      unsigned k = kb[ti][j];
      k = umax_(k, (unsigned)__builtin_amdgcn_update_dpp(0, (int)k, 0xB1, 0xF, 0xF, true));
      k = umax_(k, (unsigned)__builtin_amdgcn_update_dpp(0, (int)k, 0x4E, 0xF, 0xF, true));
      k = umax_(k, (unsigned)__builtin_amdgcn_update_dpp(0, (int)k, 0x141, 0xF, 0xF, true));
      k = umax_(k, (unsigned)__builtin_amdgcn_update_dpp(0, (int)k, 0x140, 0xF, 0xF, true));
      if (l15 == 0) kbuf[w][ti * 16 + l4 * 4 + j] = k;
    }
  __syncthreads();

  // ---- merge 4 quarters, decode, loss partial
  if (t < 64) {
    const unsigned k = umax_(umax_(kbuf[0][t], kbuf[1][t]), umax_(kbuf[2][t], kbuf[3][t]));
    sidx[t] = 1023 - (int)(k & 1023u);
    float s = __uint_as_float(~k) + 1.0f;   // t* = x.e - 0.5||e||^2
#pragma unroll
    for (int m = 1; m < 64; m <<= 1) s += __shfl_xor(s, m);
    if (t == 0) atomicAdd(acc_g, -2.f * s);
  }
  __syncthreads();

  // ---- epilogue: 2 passes of 128 c; gather -> LDS [c][hw] (stride 65) -> out
  const int b = rg >> 4;
  const int hw0 = (rg & 15) * 64;
  float* ob = out + (size_t)b * 262144 + hw0;
  const int hwR = t >> 2, cq = t & 3;
  const float* ep = emb + (size_t)sidx[hwR] * 256;
#pragma unroll
  for (int p = 0; p < 2; ++p) {
#pragma unroll
    for (int s4 = 0; s4 < 2; ++s4)
#pragma unroll
      for (int f = 0; f < 4; ++f) {
        const int cl = s4 * 64 + cq * 16 + f * 4;
        const float4 v = *(const float4*)(ep + p * 128 + cl);
        fst[(cl + 0) * 65 + hwR] = v.x;
        fst[(cl + 1) * 65 + hwR] = v.y;
        fst[(cl + 2) * 65 + hwR] = v.z;
        fst[(cl + 3) * 65 + hwR] = v.w;
      }
    __syncthreads();
#pragma unroll
    for (int i = 0; i < 8; ++i) {
      const int cl = i * 16 + (t >> 4);
      const float4 vv = *(const float4*)(fst + cl * 65 + (t & 15) * 4);
      *(float4*)(ob + (size_t)(p * 128 + cl) * 1024 + (t & 15) * 4) = vv;
    }
    __syncthreads();
  }

  if (t == 0) {
    __threadfence();
    const unsigned old = atomicAdd(done, 1u);
    if (old == 511u) {
      const float tot = atomicAdd(acc_g, 0.f);
      lossp[0] = 1.25f * tot * (1.0f / 8388608.0f);
    }
  }
}

extern "C" void kernel_launch(void* const* d_in, const int* in_sizes, int n_in,
                              void* d_out, int out_size, void* d_ws, size_t ws_size,
                              hipStream_t stream) {
  (void)in_sizes; (void)n_in; (void)ws_size;
  const float* z   = (const float*)d_in[0];
  const float* emb = (const float*)d_in[1];
  float* out = (float*)d_out;
  char* ws = (char*)d_ws;
  unsigned short* embb = (unsigned short*)ws;                 // 512 KB (tiled)
  float* h2s   = (float*)(ws + 524288);                       // 4 KB
  float* acc   = (float*)(ws + 528384);                       // 4 B
  unsigned* done = (unsigned*)(ws + 528388);                  // 4 B
  unsigned short* zb = (unsigned short*)(ws + (1 << 20));     // 16 MB (tiled)

  hipMemsetAsync(ws + 528384, 0, 8, stream);
  hipLaunchKernelGGL(k_pre, dim3(640), dim3(256), 0, stream, z, emb, embb, h2s, zb, acc);
  hipLaunchKernelGGL(k_gemm, dim3(512), dim3(256), 0, stream, zb, embb, h2s, emb,
                     out, acc, done, out + (size_t)out_size - 1);
}

// Round 14
// 70.045 us; speedup vs baseline: 1.3616x; 1.3616x over previous
//
#include <hip/hip_runtime.h>
#include <stdint.h>

typedef short bf16x8 __attribute__((ext_vector_type(8)));
typedef float f32x4 __attribute__((ext_vector_type(4)));

__device__ __forceinline__ unsigned short f2bf(float f) {
  unsigned u = __float_as_uint(f);
  u += 0x7fffu + ((u >> 16) & 1u);   // RNE round to bf16
  return (unsigned short)(u >> 16);
}
__device__ __forceinline__ unsigned umax_(unsigned a, unsigned b) { return a > b ? a : b; }

// ---- k_pre: 640 blocks. bid>=512: emb -> tiled embb + h2s.
//      bid<512: z -> fragment-tiled zb (16 rows/tile, frag=kk*4+l4) + sum z^2.
__global__ __launch_bounds__(256) void k_pre(const float* __restrict__ z,
                                             const float* __restrict__ emb,
                                             unsigned short* __restrict__ embb,
                                             float* __restrict__ h2s,
                                             unsigned short* __restrict__ zb,
                                             float* __restrict__ acc) {
  __shared__ unsigned lds[64 * 128];   // [h][cp ^ (h&28)]
  __shared__ float rsum[4];
  const int t = threadIdx.x;
  const int bid = blockIdx.x;

  if (bid >= 512) {            // ---- prep branch (128 blocks) ----
    const int n = (bid - 512) * 8 + (t >> 5);
    const int c8 = t & 31;
    const float* src = emb + (size_t)n * 256 + c8 * 8;
    float s = 0.f;
    union { bf16x8 v; unsigned short u[8]; } pk;
#pragma unroll
    for (int i = 0; i < 8; ++i) {
      float f = src[i];
      s += f * f;
      pk.u[i] = f2bf(f);
    }
    *(bf16x8*)((char*)embb + (size_t)(n >> 4) * 8192 + (c8 * 16 + (n & 15)) * 16) = pk.v;
#pragma unroll
    for (int m = 1; m < 32; m <<= 1) s += __shfl_xor(s, m);
    if ((t & 31) == 0) h2s[n] = 0.5f * s + 1.0f;   // +1 keeps scores strictly < 0
    return;
  }

  // ---- prez branch (512 blocks): 64 hw-rows x 256 c ----
  const int b = bid >> 4, hwg = bid & 15;
  const int tc = t >> 4, h4 = (t & 15) * 4;
  const float* zp = z + (size_t)b * 262144 + hwg * 64;
  float ss = 0.f;
#pragma unroll
  for (int p = 0; p < 8; ++p) {
    const int cp = p * 16 + tc;                       // c-pair index 0..127
    const float4 v0 = *(const float4*)(zp + (size_t)(2 * cp) * 1024 + h4);
    const float4 v1 = *(const float4*)(zp + (size_t)(2 * cp + 1) * 1024 + h4);
    ss += v0.x * v0.x + v0.y * v0.y + v0.z * v0.z + v0.w * v0.w
        + v1.x * v1.x + v1.y * v1.y + v1.z * v1.z + v1.w * v1.w;
    const unsigned w0 = ((unsigned)f2bf(v1.x) << 16) | (unsigned)f2bf(v0.x);
    const unsigned w1 = ((unsigned)f2bf(v1.y) << 16) | (unsigned)f2bf(v0.y);
    const unsigned w2 = ((unsigned)f2bf(v1.z) << 16) | (unsigned)f2bf(v0.z);
    const unsigned w3 = ((unsigned)f2bf(v1.w) << 16) | (unsigned)f2bf(v0.w);
    lds[(h4 + 0) * 128 + (cp ^ ((h4 + 0) & 28))] = w0;
    lds[(h4 + 1) * 128 + (cp ^ ((h4 + 1) & 28))] = w1;
    lds[(h4 + 2) * 128 + (cp ^ ((h4 + 2) & 28))] = w2;
    lds[(h4 + 3) * 128 + (cp ^ ((h4 + 3) & 28))] = w3;
  }
#pragma unroll
  for (int m = 1; m < 64; m <<= 1) ss += __shfl_xor(ss, m);
  if ((t & 63) == 0) rsum[t >> 6] = ss;
  __syncthreads();
  if (t == 0) atomicAdd(acc, rsum[0] + rsum[1] + rsum[2] + rsum[3]);

  unsigned* zbd = (unsigned*)zb;
  const size_t base_dw = ((size_t)b * 1024 + hwg * 64) * 128;
  const int l15 = t & 15, fr = t >> 4;                // fr 0..15
#pragma unroll
  for (int tile = 0; tile < 4; ++tile) {
    const int r = tile * 16 + l15;
#pragma unroll
    for (int half = 0; half < 2; ++half) {
      const int frag = fr + half * 16;                // 0..31 = kk*4+l4
      const int d = (frag >> 2) * 16 + (frag & 3) * 4;
      uint4 v = *(const uint4*)(&lds[r * 128 + (d ^ (r & 28))]);
      *(uint4*)(zbd + base_dw + tile * 2048 + frag * 64 + l15 * 4) = v;
    }
  }
}

// ---- k_gemm: 512 blocks x 4 waves. Wave = 64 rows (af[4][8] in regs) x
// 256-emb quarter. launch_bounds(256,1): allocator gets ~240 VGPR spill-free
// (R13's (256,2) forced a 128 cap -> ~100 spilled regs -> 160MB scratch traffic).
__global__ __launch_bounds__(256, 1) void k_gemm(
    const unsigned short* __restrict__ zb, const unsigned short* __restrict__ embb,
    const float* __restrict__ h2s, const float* __restrict__ emb,
    float* __restrict__ out, float* __restrict__ acc_g,
    unsigned* __restrict__ done, float* __restrict__ lossp) {

  __shared__ __align__(16) float fst[128 * 65];   // epilogue staging (33 KB)
  __shared__ __align__(16) float hL[1024];
  __shared__ unsigned kbuf[4][64];
  __shared__ int sidx[64];

  const int t = threadIdx.x;
  const int lane = t & 63;
  const int w = t >> 6;            // emb quarter
  const int l15 = lane & 15;
  const int l4 = lane >> 4;
  const int rg = blockIdx.x;

  ((float4*)hL)[t] = *(const float4*)(h2s + t * 4);

  // A: 64 rows resident in registers (32 contiguous-1KB loads from tiled zb)
  const char* Az = (const char*)zb + (size_t)rg * 32768 + l4 * 256 + l15 * 16;
  bf16x8 af[4][8];
#pragma unroll
  for (int ti = 0; ti < 4; ++ti)
#pragma unroll
    for (int kk = 0; kk < 8; ++kk)
      af[ti][kk] = *(const bf16x8*)(Az + ti * 8192 + kk * 1024);

  __syncthreads();   // hL visible

  const char* Bp = (const char*)embb;
  // quarter stride: 256 embs x 512 B = 131072 B
  const unsigned off0 = (unsigned)(w * 131072 + l4 * 256 + l15 * 16);
  const unsigned ciob = (unsigned)(1023 - (w * 256 + l15));
  unsigned kb[4][4];
#pragma unroll
  for (int ti = 0; ti < 4; ++ti)
#pragma unroll
    for (int j = 0; j < 4; ++j) kb[ti][j] = 0u;

  bf16x8 bufA[8], bufB[8];

#define LOAD8(DST, OFF, OFFH)                                                                     \
  asm volatile("global_load_dwordx4 %0, %1, %2 offset:0"    : "=v"(DST[0]) : "v"(OFF),  "s"(Bp)); \
  asm volatile("global_load_dwordx4 %0, %1, %2 offset:1024" : "=v"(DST[1]) : "v"(OFF),  "s"(Bp)); \
  asm volatile("global_load_dwordx4 %0, %1, %2 offset:2048" : "=v"(DST[2]) : "v"(OFF),  "s"(Bp)); \
  asm volatile("global_load_dwordx4 %0, %1, %2 offset:3072" : "=v"(DST[3]) : "v"(OFF),  "s"(Bp)); \
  asm volatile("global_load_dwordx4 %0, %1, %2 offset:0"    : "=v"(DST[4]) : "v"(OFFH), "s"(Bp)); \
  asm volatile("global_load_dwordx4 %0, %1, %2 offset:1024" : "=v"(DST[5]) : "v"(OFFH), "s"(Bp)); \
  asm volatile("global_load_dwordx4 %0, %1, %2 offset:2048" : "=v"(DST[6]) : "v"(OFFH), "s"(Bp)); \
  asm volatile("global_load_dwordx4 %0, %1, %2 offset:3072" : "=v"(DST[7]) : "v"(OFFH), "s"(Bp));

  LOAD8(bufA, off0, off0 + 4096u)   // tile 0 in flight

#pragma unroll
  for (int tl = 0; tl < 16; ++tl) {
    bf16x8 (&cur)[8] = (tl & 1) ? bufB : bufA;
    bf16x8 (&nxt)[8] = (tl & 1) ? bufA : bufB;
    if (tl < 15) {
      const unsigned oN = off0 + (unsigned)((tl + 1) * 8192);
      LOAD8(nxt, oN, oN + 4096u)
      asm volatile("s_waitcnt vmcnt(8)" ::: "memory");   // tile tl arrived
    } else {
      asm volatile("s_waitcnt vmcnt(0)" ::: "memory");
    }
    __builtin_amdgcn_sched_barrier(0);                   // rule #18 fence
    const float hv = hL[w * 256 + tl * 16 + l15];
    f32x4 a0{}, a1{}, a2{}, a3{};
#pragma unroll
    for (int kk = 0; kk < 8; ++kk) {
      a0 = __builtin_amdgcn_mfma_f32_16x16x32_bf16(af[0][kk], cur[kk], a0, 0, 0, 0);
      a1 = __builtin_amdgcn_mfma_f32_16x16x32_bf16(af[1][kk], cur[kk], a1, 0, 0, 0);
      a2 = __builtin_amdgcn_mfma_f32_16x16x32_bf16(af[2][kk], cur[kk], a2, 0, 0, 0);
      a3 = __builtin_amdgcn_mfma_f32_16x16x32_bf16(af[3][kk], cur[kk], a3, 0, 0, 0);
    }
    const unsigned cio = ciob - (unsigned)(tl * 16);
#pragma unroll
    for (int j = 0; j < 4; ++j) {
      kb[0][j] = umax_(kb[0][j], (~__float_as_uint(a0[j] - hv) & 0xFFFFFC00u) | cio);
      kb[1][j] = umax_(kb[1][j], (~__float_as_uint(a1[j] - hv) & 0xFFFFFC00u) | cio);
      kb[2][j] = umax_(kb[2][j], (~__float_as_uint(a2[j] - hv) & 0xFFFFFC00u) | cio);
      kb[3][j] = umax_(kb[3][j], (~__float_as_uint(a3[j] - hv) & 0xFFFFFC00u) | cio);
    }
  }
#undef LOAD8

  // ---- 16-lane DPP key-max per (ti,j) -> kbuf[w]
#pragma unroll
  for (int ti = 0; ti < 4; ++ti)
#pragma unroll
    for (int j = 0; j < 4; ++j) {
      unsigned k = kb[ti][j];
      k = umax_(k, (unsigned)__builtin_amdgcn_update_dpp(0, (int)k, 0xB1, 0xF, 0xF, true));
      k = umax_(k, (unsigned)__builtin_amdgcn_update_dpp(0, (int)k, 0x4E, 0xF, 0xF, true));
      k = umax_(k, (unsigned)__builtin_amdgcn_update_dpp(0, (int)k, 0x141, 0xF, 0xF, true));
      k = umax_(k, (unsigned)__builtin_amdgcn_update_dpp(0, (int)k, 0x140, 0xF, 0xF, true));
      if (l15 == 0) kbuf[w][ti * 16 + l4 * 4 + j] = k;
    }
  __syncthreads();

  // ---- merge 4 quarters, decode, loss partial
  if (t < 64) {
    const unsigned k = umax_(umax_(kbuf[0][t], kbuf[1][t]), umax_(kbuf[2][t], kbuf[3][t]));
    sidx[t] = 1023 - (int)(k & 1023u);
    float s = __uint_as_float(~k) + 1.0f;   // t* = x.e - 0.5||e||^2
#pragma unroll
    for (int m = 1; m < 64; m <<= 1) s += __shfl_xor(s, m);
    if (t == 0) atomicAdd(acc_g, -2.f * s);
  }
  __syncthreads();

  // ---- epilogue: 2 passes of 128 c; gather -> LDS [c][hw] (stride 65) -> out
  const int b = rg >> 4;
  const int hw0 = (rg & 15) * 64;
  float* ob = out + (size_t)b * 262144 + hw0;
  const int hwR = t >> 2, cq = t & 3;
  const float* ep = emb + (size_t)sidx[hwR] * 256;
#pragma unroll
  for (int p = 0; p < 2; ++p) {
#pragma unroll
    for (int s4 = 0; s4 < 2; ++s4)
#pragma unroll
      for (int f = 0; f < 4; ++f) {
        const int cl = s4 * 64 + cq * 16 + f * 4;
        const float4 v = *(const float4*)(ep + p * 128 + cl);
        fst[(cl + 0) * 65 + hwR] = v.x;
        fst[(cl + 1) * 65 + hwR] = v.y;
        fst[(cl + 2) * 65 + hwR] = v.z;
        fst[(cl + 3) * 65 + hwR] = v.w;
      }
    __syncthreads();
#pragma unroll
    for (int i = 0; i < 8; ++i) {
      const int cl = i * 16 + (t >> 4);
      const float4 vv = *(const float4*)(fst + cl * 65 + (t & 15) * 4);
      *(float4*)(ob + (size_t)(p * 128 + cl) * 1024 + (t & 15) * 4) = vv;
    }
    __syncthreads();
  }

  if (t == 0) {
    __threadfence();
    const unsigned old = atomicAdd(done, 1u);
    if (old == 511u) {
      const float tot = atomicAdd(acc_g, 0.f);
      lossp[0] = 1.25f * tot * (1.0f / 8388608.0f);
    }
  }
}

extern "C" void kernel_launch(void* const* d_in, const int* in_sizes, int n_in,
                              void* d_out, int out_size, void* d_ws, size_t ws_size,
                              hipStream_t stream) {
  (void)in_sizes; (void)n_in; (void)ws_size;
  const float* z   = (const float*)d_in[0];
  const float* emb = (const float*)d_in[1];
  float* out = (float*)d_out;
  char* ws = (char*)d_ws;
  unsigned short* embb = (unsigned short*)ws;                 // 512 KB (tiled)
  float* h2s   = (float*)(ws + 524288);                       // 4 KB
  float* acc   = (float*)(ws + 528384);                       // 4 B
  unsigned* done = (unsigned*)(ws + 528388);                  // 4 B
  unsigned short* zb = (unsigned short*)(ws + (1 << 20));     // 16 MB (tiled)

  hipMemsetAsync(ws + 528384, 0, 8, stream);
  hipLaunchKernelGGL(k_pre, dim3(640), dim3(256), 0, stream, z, emb, embb, h2s, zb, acc);
  hipLaunchKernelGGL(k_gemm, dim3(512), dim3(256), 0, stream, zb, embb, h2s, emb,
                     out, acc, done, out + (size_t)out_size - 1);
}